// Round 2
// baseline (1219.386 us; speedup 1.0000x reference)
//
#include <hip/hip_runtime.h>
#include <stdint.h>

// BinHD: samples [8192,10000] f32 {0,1}, classes [1000,10000] f32 {0,1}
// out [8192,1000] f32 = exact Hamming distance via popcount(xor) on bit-packed rows.
#define N_ROWS 8192
#define C_CLS  1000
#define D_DIM  10000
#define W64P   160            // u64 words per packed row (157.x used, rest zero)
#define W32P   (W64P * 2)     // 320 u32 words per packed row
#define KW     32             // u32 words per K-chunk (128 B per row per chunk)
#define NCHUNK 10             // 10 * 32 = 320 words

// ---------------------------------------------------------------------------
// Kernel 1: bit-pack fp32 {0,1} rows into u64 words, float4 + 4 ballots/iter.
// Bit order: dim d -> word (d/256)*4 + (d%4), bit (d%256)/4.  Fixed permutation
// applied identically to samples and classes => popc(xor) (Hamming) unchanged.
// Writes ALL 160 words/row (padding dims -> 0 bits): fully initializes the
// poisoned workspace region we later read.
// ---------------------------------------------------------------------------
__global__ __launch_bounds__(256) void pack_kernel(
    const float* __restrict__ samples, const float* __restrict__ classes,
    unsigned long long* __restrict__ pA, unsigned long long* __restrict__ pB)
{
    int gwave = (blockIdx.x * 256 + threadIdx.x) >> 6;
    int lane  = threadIdx.x & 63;
    if (gwave >= N_ROWS + C_CLS) return;   // wave-uniform exit

    const float* src;
    unsigned long long* dst;
    if (gwave < N_ROWS) {
        src = samples + (size_t)gwave * D_DIM;
        dst = pA + (size_t)gwave * W64P;
    } else {
        int r = gwave - N_ROWS;
        src = classes + (size_t)r * D_DIM;
        dst = pB + (size_t)r * W64P;
    }

    #pragma unroll 4
    for (int w = 0; w < 40; ++w) {         // 40 * 4 = 160 u64 words
        int idx = w * 256 + lane * 4;      // 16B/lane, coalesced 1KB/wave
        float4 v = make_float4(0.f, 0.f, 0.f, 0.f);
        if (idx < D_DIM) v = *(const float4*)(src + idx);   // D_DIM%4==0
        unsigned long long m0 = __ballot(v.x > 0.5f);
        unsigned long long m1 = __ballot(v.y > 0.5f);
        unsigned long long m2 = __ballot(v.z > 0.5f);
        unsigned long long m3 = __ballot(v.w > 0.5f);
        if (lane == 0) {
            uint4 p0, p1;
            p0.x = (uint32_t)m0; p0.y = (uint32_t)(m0 >> 32);
            p0.z = (uint32_t)m1; p0.w = (uint32_t)(m1 >> 32);
            p1.x = (uint32_t)m2; p1.y = (uint32_t)(m2 >> 32);
            p1.z = (uint32_t)m3; p1.w = (uint32_t)(m3 >> 32);
            *(uint4*)(dst + (size_t)w * 4)     = p0;
            *(uint4*)(dst + (size_t)w * 4 + 2) = p1;
        }
    }
}

// ---------------------------------------------------------------------------
// Kernel 2: Hamming "GEMM": out[n,c] = sum_w popc(A[n,w] ^ B[c,w]).
// Occupancy-first restructure vs prev round (which sat at 1 wave/SIMD,
// VGPR=256, VALUBusy 60%):
//   - 128x64 tile per 256-thread block, 8x4 accs/thread (32 acc regs).
//   - __launch_bounds__(256,3): cap allocator at 168 VGPR -> 3 waves/SIMD.
//   - LDS 48 KB/block (dbuf) -> 3 blocks/CU co-resident (12 waves/CU).
//   - global_load_lds DMA staging, ONE barrier per chunk (unchanged pattern).
// Swizzle (rule #21, both-sides): LDS dest linear; per-lane GLOBAL source
// carries the XOR, ds_reads apply the same XOR.
//   A: key(row) = (row>>3)&7 -> reads: 4 addrs in 4 distinct bank groups (free)
//   B: key(row) = (row>>2)&7 -> reads: 8 groups / 16 addrs = 2-way (free)
// B tail: source col clamped to 999; those accs map to cols >= 1000 which the
// epilogue never stores.
// ---------------------------------------------------------------------------
__global__ __launch_bounds__(256, 3) void hd_kernel(
    const uint32_t* __restrict__ pA, const uint32_t* __restrict__ pB,
    float* __restrict__ out)
{
    __shared__ uint32_t As[2][128 * KW];   // 2 x 16 KB
    __shared__ uint32_t Bs[2][64 * KW];    // 2 x  8 KB  (total 48 KB)

    const int tid  = threadIdx.x;
    const int row0 = blockIdx.x * 128;     // 64 row tiles
    const int col0 = blockIdx.y * 64;      // 16 col tiles (1024 padded cols)

    const int w    = tid >> 6;             // wave 0..3
    const int lane = tid & 63;
    const int tr   = tid >> 4;             // thread-row 0..15 (wave-contig: w*4 + lane>>4)
    const int tc   = tid & 15;             // thread-col 0..15
    const int trow = tr * 8;               // 8 output rows per thread
    const int tcol = tc * 4;               // 4 output cols per thread
    const int ka   = tr & 7;               // A read swizzle key  ((row>>3)&7)
    const int kb   = tc & 7;               // B read swizzle key  ((row>>2)&7, row=tc*4+c)

    // Per-lane DMA source pointers (pre-swizzled); LDS bases wave-uniform.
    // Each global_load_lds (size=16) stages 1 KB = one 8-row x 32-word span.
    const uint32_t* gA[4];                 // A spans: sp = w + 4*i, i=0..3  (16 spans)
    const uint32_t* gB[2];                 // B spans: sp = w + 4*i, i=0..1  ( 8 spans)
    uint32_t*       lA[4];
    uint32_t*       lB[2];
    #pragma unroll
    for (int i = 0; i < 4; ++i) {
        int sp   = w + 4 * i;              // 0..15
        int rr   = sp * 8 + (lane >> 3);   // row within 128-tile
        int gsrc = (lane & 7) ^ (sp & 7);  // key_A(row) = (row>>3)&7 = sp&7
        gA[i] = pA + (size_t)(row0 + rr) * W32P + gsrc * 4;
        lA[i] = &As[0][sp * 256];          // + buf*(128*KW) selects buffer
    }
    #pragma unroll
    for (int i = 0; i < 2; ++i) {
        int sp   = w + 4 * i;              // 0..7
        int rr   = sp * 8 + (lane >> 3);
        int key  = ((sp << 1) + (lane >> 5)) & 7;  // key_B(row) = (row>>2)&7
        int gsrc = (lane & 7) ^ key;
        int gc   = col0 + rr;
        if (gc >= C_CLS) gc = C_CLS - 1;   // clamp: results for cols>=1000 discarded
        gB[i] = pB + (size_t)gc * W32P + gsrc * 4;
        lB[i] = &Bs[0][sp * 256];          // + buf*(64*KW)
    }

#define STAGE(ch, buf) do {                                                        \
    _Pragma("unroll")                                                              \
    for (int i = 0; i < 4; ++i)                                                    \
        __builtin_amdgcn_global_load_lds(                                          \
            (const __attribute__((address_space(1))) uint32_t*)(gA[i] + (ch) * KW),\
            (__attribute__((address_space(3))) uint32_t*)(lA[i] + (buf) * (128 * KW)), \
            16, 0, 0);                                                             \
    _Pragma("unroll")                                                              \
    for (int i = 0; i < 2; ++i)                                                    \
        __builtin_amdgcn_global_load_lds(                                          \
            (const __attribute__((address_space(1))) uint32_t*)(gB[i] + (ch) * KW),\
            (__attribute__((address_space(3))) uint32_t*)(lB[i] + (buf) * (64 * KW)),  \
            16, 0, 0);                                                             \
} while (0)

    uint32_t acc[8][4];
    #pragma unroll
    for (int r = 0; r < 8; ++r)
        #pragma unroll
        for (int c = 0; c < 4; ++c) acc[r][c] = 0;

    STAGE(0, 0);
    __syncthreads();                        // drain chunk-0 DMA

    for (int ch = 0; ch < NCHUNK; ++ch) {   // NOT unrolled: keep body in I-cache
        const int cur = ch & 1;
        if (ch + 1 < NCHUNK) STAGE(ch + 1, cur ^ 1);   // async, hides under compute

        const uint32_t* Ab = &As[0][0] + cur * (128 * KW);
        const uint32_t* Bb = &Bs[0][0] + cur * (64 * KW);

        #pragma unroll
        for (int g = 0; g < 8; ++g) {       // 16B sub-group of the 128B chunk-row
            uint4 a[8], b[4];
            #pragma unroll
            for (int r = 0; r < 8; ++r)
                a[r] = *(const uint4*)&Ab[(trow + r) * KW + ((g ^ ka) << 2)];
            #pragma unroll
            for (int c = 0; c < 4; ++c)
                b[c] = *(const uint4*)&Bb[(tcol + c) * KW + ((g ^ kb) << 2)];
            #pragma unroll
            for (int r = 0; r < 8; ++r)
                #pragma unroll
                for (int c = 0; c < 4; ++c) {
                    acc[r][c] += __popc(a[r].x ^ b[c].x);
                    acc[r][c] += __popc(a[r].y ^ b[c].y);
                    acc[r][c] += __popc(a[r].z ^ b[c].z);
                    acc[r][c] += __popc(a[r].w ^ b[c].w);
                }
        }
        __syncthreads();   // vmcnt(0)+barrier: next-chunk DMA done, cur reads done
    }
#undef STAGE

    // ---- epilogue: exact integer -> f32, float4 stores (1000 % 4 == 0) ----
    #pragma unroll
    for (int r = 0; r < 8; ++r) {
        int grow = row0 + trow + r;
        int gcol = col0 + tcol;
        if (gcol < C_CLS) {
            float4 v = make_float4((float)acc[r][0], (float)acc[r][1],
                                   (float)acc[r][2], (float)acc[r][3]);
            *(float4*)(out + (size_t)grow * C_CLS + gcol) = v;
        }
    }
}

extern "C" void kernel_launch(void* const* d_in, const int* in_sizes, int n_in,
                              void* d_out, int out_size, void* d_ws, size_t ws_size,
                              hipStream_t stream) {
    const float* samples = (const float*)d_in[0];   // [8192, 10000] f32
    const float* classes = (const float*)d_in[1];   // [1000, 10000] f32
    float* out = (float*)d_out;                     // [8192, 1000] f32

    // Workspace layout: packed A (8192*160 u64 = 10.49 MB) then packed B (1.28 MB)
    unsigned long long* pA = (unsigned long long*)d_ws;
    unsigned long long* pB = pA + (size_t)N_ROWS * W64P;

    int waves  = N_ROWS + C_CLS;             // one wave per row
    int blocks = (waves + 3) / 4;            // 4 waves per 256-thread block
    pack_kernel<<<blocks, 256, 0, stream>>>(samples, classes, pA, pB);

    dim3 grid(N_ROWS / 128, 16);             // 64 x 16 = 1024 blocks (3/CU resident)
    hd_kernel<<<grid, 256, 0, stream>>>((const uint32_t*)pA, (const uint32_t*)pB, out);
}

// Round 3
// 576.657 us; speedup vs baseline: 2.1146x; 2.1146x over previous
//
#include <hip/hip_runtime.h>
#include <stdint.h>

// BinHD: samples [8192,10000] f32 {0,1}, classes [1000,10000] f32 {0,1}
// out [8192,1000] f32 = exact Hamming distance.
// v3: i8 MFMA path. Bits -> {+1,-1} i8, dist = (DP - dot)/2 exactly.
#define N_ROWS 8192
#define C_CLS  1000
#define D_DIM  10000
#define W64P   160            // u64 words per packed row (pad bits are 0)
#define W32P   (W64P * 2)     // 320 u32 words per packed row
#define DP     (W32P * 32)    // 10240 padded dims; pads are -1 on BOTH sides -> cancel
#define BKW    16             // u32 words per row per chunk (512 dims)
#define NCHUNK 20             // 20 * 16 = 320 words

typedef int v4i  __attribute__((ext_vector_type(4)));
typedef int v16i __attribute__((ext_vector_type(16)));

// ---------------------------------------------------------------------------
// Kernel 1 (unchanged, proven): bit-pack fp32 {0,1} rows into u64 words.
// Fixed dim permutation identical for A and B => Hamming invariant.
// Writes ALL 160 words/row -> poisoned ws fully initialized.
// ---------------------------------------------------------------------------
__global__ __launch_bounds__(256) void pack_kernel(
    const float* __restrict__ samples, const float* __restrict__ classes,
    unsigned long long* __restrict__ pA, unsigned long long* __restrict__ pB)
{
    int gwave = (blockIdx.x * 256 + threadIdx.x) >> 6;
    int lane  = threadIdx.x & 63;
    if (gwave >= N_ROWS + C_CLS) return;   // wave-uniform exit

    const float* src;
    unsigned long long* dst;
    if (gwave < N_ROWS) {
        src = samples + (size_t)gwave * D_DIM;
        dst = pA + (size_t)gwave * W64P;
    } else {
        int r = gwave - N_ROWS;
        src = classes + (size_t)r * D_DIM;
        dst = pB + (size_t)r * W64P;
    }

    #pragma unroll 4
    for (int w = 0; w < 40; ++w) {         // 40 * 4 = 160 u64 words
        int idx = w * 256 + lane * 4;      // 16B/lane, coalesced 1KB/wave
        float4 v = make_float4(0.f, 0.f, 0.f, 0.f);
        if (idx < D_DIM) v = *(const float4*)(src + idx);   // D_DIM%4==0
        unsigned long long m0 = __ballot(v.x > 0.5f);
        unsigned long long m1 = __ballot(v.y > 0.5f);
        unsigned long long m2 = __ballot(v.z > 0.5f);
        unsigned long long m3 = __ballot(v.w > 0.5f);
        if (lane == 0) {
            uint4 p0, p1;
            p0.x = (uint32_t)m0; p0.y = (uint32_t)(m0 >> 32);
            p0.z = (uint32_t)m1; p0.w = (uint32_t)(m1 >> 32);
            p1.x = (uint32_t)m2; p1.y = (uint32_t)(m2 >> 32);
            p1.z = (uint32_t)m3; p1.w = (uint32_t)(m3 >> 32);
            *(uint4*)(dst + (size_t)w * 4)     = p0;
            *(uint4*)(dst + (size_t)w * 4 + 2) = p1;
        }
    }
}

// ---------------------------------------------------------------------------
// Kernel 2: Hamming GEMM on matrix cores.
//   dot[n,c] = sum_d s_d * c_d with s,c in {+1,-1};  dist = (DP - dot)/2 exact.
// Block: 256 thr (4 waves, 2x2), tile 128x128; wave tile 64x64 = 2x2 MFMAs
// of v_mfma_i32_32x32x32_i8 (acc 4 x 16 i32). Grid 64x8 = 512 blocks.
// K: 20 chunks of 512 dims. LDS holds PACKED bits, transposed [step][row]
// (4KB+... 8KB A + 8KB B per buf, dbuf = 32KB): ds_read_b32 addr =
// s*128+(lane&31) -> 32 addrs / 32 banks, halves broadcast: conflict-free,
// no swizzle. Bits unpacked LDS->reg to +-1 bytes per fragment:
//   t = (w >> (4h+j)) & 0x01010101;  frag[j] = (t*0xFE) ^ ~0u   (bytes 01/FF)
// The induced dim permutation is identical for A and B -> cancels in dot.
// Reg-staged global->LDS (loads issued before compute, T14), ONE barrier
// per chunk. No launch_bounds min-waves (round-2 spill lesson).
// ---------------------------------------------------------------------------
__global__ __launch_bounds__(256) void hd_kernel(
    const uint32_t* __restrict__ pA, const uint32_t* __restrict__ pB,
    float* __restrict__ out)
{
    __shared__ uint32_t AsT[2][BKW][128];   // [buf][step][row]  2 x 8 KB
    __shared__ uint32_t BsT[2][BKW][128];   // [buf][step][col]  2 x 8 KB

    const int tid  = threadIdx.x;
    const int row0 = blockIdx.x * 128;      // 64 row tiles
    const int col0 = blockIdx.y * 128;      // 8 col tiles (1024 padded)

    const int w    = tid >> 6;              // wave 0..3
    const int lane = tid & 63;
    const int wy   = w >> 1;                // wave row half (64 rows)
    const int wx   = w & 1;                 // wave col half (64 cols)
    const int ln   = lane & 31;             // row/col within 32-tile
    const int h4   = (lane >> 5) * 4;       // k-half shift base

    // Staging roles: thread covers row srow = tid>>1, 32B half sq2 = (tid&1)*2.
    const int srow = tid >> 1;              // 0..127
    const int sq2  = (tid & 1) * 2;         // q = sq2 + i, i = 0..1
    const uint32_t* gAs = pA + (size_t)(row0 + srow) * W32P + sq2 * 4;
    int gc = col0 + srow; if (gc >= C_CLS) gc = C_CLS - 1;  // clamped cols never stored
    const uint32_t* gBs = pB + (size_t)gc * W32P + sq2 * 4;

    uint4 av[2], bv[2];                     // in-flight staging regs (T14)

#define LOADR(ch) do {                                             \
    av[0] = *(const uint4*)(gAs + (ch) * BKW);                     \
    av[1] = *(const uint4*)(gAs + (ch) * BKW + 4);                 \
    bv[0] = *(const uint4*)(gBs + (ch) * BKW);                     \
    bv[1] = *(const uint4*)(gBs + (ch) * BKW + 4);                 \
} while (0)

    // transpose-write: word k of quad q -> step s = q*4+k, slot [s][srow].
    // banks = srow%32 (128%32==0), 2 q-threads/row same bank diff addr: 2-way, free.
#define WRITELDS(buf) do {                                         \
    AsT[buf][sq2 * 4 + 0][srow] = av[0].x;                         \
    AsT[buf][sq2 * 4 + 1][srow] = av[0].y;                         \
    AsT[buf][sq2 * 4 + 2][srow] = av[0].z;                         \
    AsT[buf][sq2 * 4 + 3][srow] = av[0].w;                         \
    AsT[buf][sq2 * 4 + 4][srow] = av[1].x;                         \
    AsT[buf][sq2 * 4 + 5][srow] = av[1].y;                         \
    AsT[buf][sq2 * 4 + 6][srow] = av[1].z;                         \
    AsT[buf][sq2 * 4 + 7][srow] = av[1].w;                         \
    BsT[buf][sq2 * 4 + 0][srow] = bv[0].x;                         \
    BsT[buf][sq2 * 4 + 1][srow] = bv[0].y;                         \
    BsT[buf][sq2 * 4 + 2][srow] = bv[0].z;                         \
    BsT[buf][sq2 * 4 + 3][srow] = bv[0].w;                         \
    BsT[buf][sq2 * 4 + 4][srow] = bv[1].x;                         \
    BsT[buf][sq2 * 4 + 5][srow] = bv[1].y;                         \
    BsT[buf][sq2 * 4 + 6][srow] = bv[1].z;                         \
    BsT[buf][sq2 * 4 + 7][srow] = bv[1].w;                         \
} while (0)

    // bit-word -> 16 x i8 {+1,-1} fragment (lane's k-half selected by h4)
#define UNPACK(dst, src) do {                                      \
    uint32_t t_;                                                   \
    t_ = ((src) >> (h4 + 0)) & 0x01010101u;                        \
    dst[0] = (int)((t_ * 0xFEu) ^ 0xFFFFFFFFu);                    \
    t_ = ((src) >> (h4 + 1)) & 0x01010101u;                        \
    dst[1] = (int)((t_ * 0xFEu) ^ 0xFFFFFFFFu);                    \
    t_ = ((src) >> (h4 + 2)) & 0x01010101u;                        \
    dst[2] = (int)((t_ * 0xFEu) ^ 0xFFFFFFFFu);                    \
    t_ = ((src) >> (h4 + 3)) & 0x01010101u;                        \
    dst[3] = (int)((t_ * 0xFEu) ^ 0xFFFFFFFFu);                    \
} while (0)

    v16i acc00 = {}, acc01 = {}, acc10 = {}, acc11 = {};

    LOADR(0);
    WRITELDS(0);
    __syncthreads();

    #pragma unroll 2
    for (int ch = 0; ch < NCHUNK; ++ch) {
        const int cur = ch & 1;
        if (ch + 1 < NCHUNK) LOADR(ch + 1);   // issue early; consumed after compute

        const uint32_t* Ac = &AsT[cur][0][0];
        const uint32_t* Bc = &BsT[cur][0][0];

        #pragma unroll
        for (int s = 0; s < BKW; ++s) {       // one MFMA K=32 step per word
            uint32_t wa0 = Ac[s * 128 + wy * 64 + ln];
            uint32_t wa1 = Ac[s * 128 + wy * 64 + 32 + ln];
            uint32_t wb0 = Bc[s * 128 + wx * 64 + ln];
            uint32_t wb1 = Bc[s * 128 + wx * 64 + 32 + ln];
            v4i a0, a1, b0, b1;
            UNPACK(a0, wa0);
            UNPACK(a1, wa1);
            UNPACK(b0, wb0);
            UNPACK(b1, wb1);
            acc00 = __builtin_amdgcn_mfma_i32_32x32x32_i8(a0, b0, acc00, 0, 0, 0);
            acc01 = __builtin_amdgcn_mfma_i32_32x32x32_i8(a0, b1, acc01, 0, 0, 0);
            acc10 = __builtin_amdgcn_mfma_i32_32x32x32_i8(a1, b0, acc10, 0, 0, 0);
            acc11 = __builtin_amdgcn_mfma_i32_32x32x32_i8(a1, b1, acc11, 0, 0, 0);
        }

        if (ch + 1 < NCHUNK) {
            WRITELDS((ch + 1) & 1);   // other buffer: disjoint from cur readers
            __syncthreads();          // writes visible before next chunk's reads
        }
    }
#undef LOADR
#undef WRITELDS
#undef UNPACK

    // ---- epilogue: C/D layout (32x32): col = lane&31, row = (r&3)+8*(r>>2)+4*(lane>>5)
    const int mh = h4;                // 4*(lane>>5)
    #pragma unroll
    for (int r = 0; r < 16; ++r) {
        const int m = (r & 3) + 8 * (r >> 2) + mh;
        {   // tile (0,0)
            int grow = row0 + wy * 64 + m;
            int gcol = col0 + wx * 64 + ln;
            if (gcol < C_CLS)
                out[(size_t)grow * C_CLS + gcol] = (float)((DP - acc00[r]) >> 1);
        }
        {   // tile (0,1)
            int grow = row0 + wy * 64 + m;
            int gcol = col0 + wx * 64 + 32 + ln;
            if (gcol < C_CLS)
                out[(size_t)grow * C_CLS + gcol] = (float)((DP - acc01[r]) >> 1);
        }
        {   // tile (1,0)
            int grow = row0 + wy * 64 + 32 + m;
            int gcol = col0 + wx * 64 + ln;
            if (gcol < C_CLS)
                out[(size_t)grow * C_CLS + gcol] = (float)((DP - acc10[r]) >> 1);
        }
        {   // tile (1,1)
            int grow = row0 + wy * 64 + 32 + m;
            int gcol = col0 + wx * 64 + 32 + ln;
            if (gcol < C_CLS)
                out[(size_t)grow * C_CLS + gcol] = (float)((DP - acc11[r]) >> 1);
        }
    }
}

extern "C" void kernel_launch(void* const* d_in, const int* in_sizes, int n_in,
                              void* d_out, int out_size, void* d_ws, size_t ws_size,
                              hipStream_t stream) {
    const float* samples = (const float*)d_in[0];   // [8192, 10000] f32
    const float* classes = (const float*)d_in[1];   // [1000, 10000] f32
    float* out = (float*)d_out;                     // [8192, 1000] f32

    // Workspace: packed A (10.49 MB) then packed B (1.28 MB) — unchanged.
    unsigned long long* pA = (unsigned long long*)d_ws;
    unsigned long long* pB = pA + (size_t)N_ROWS * W64P;

    int waves  = N_ROWS + C_CLS;
    int blocks = (waves + 3) / 4;
    pack_kernel<<<blocks, 256, 0, stream>>>(samples, classes, pA, pB);

    dim3 grid(N_ROWS / 128, 8);              // 512 blocks
    hd_kernel<<<grid, 256, 0, stream>>>((const uint32_t*)pA, (const uint32_t*)pB, out);
}

// Round 4
// 543.560 us; speedup vs baseline: 2.2433x; 1.0609x over previous
//
#include <hip/hip_runtime.h>
#include <stdint.h>

// BinHD: samples [8192,10000] f32 {0,1}, classes [1000,10000] f32 {0,1}
// out [8192,1000] f32 = exact Hamming distance.
// v4: i8 MFMA with {0,1} bytes + row-popcount correction:
//   dot01[n,c] = sum_d a_d*b_d (a,b in {0,1});  dist = rsA[n] + rsB[c] - 2*dot01.
// Pad bits are 0 on both sides -> contribute 0 to dot and rowsums. Exact.
#define N_ROWS 8192
#define C_CLS  1000
#define D_DIM  10000
#define W64P   160            // u64 words per packed row (pad bits are 0)
#define W32P   (W64P * 2)     // 320 u32 words per packed row
#define BKW    16             // u32 words per row per chunk (512 dims)
#define NCHUNK 20             // 20 * 16 = 320 words

typedef int v4i  __attribute__((ext_vector_type(4)));
typedef int v16i __attribute__((ext_vector_type(16)));

// ---------------------------------------------------------------------------
// Kernel 1: bit-pack fp32 {0,1} rows into u64 words + per-row popcount.
// Fixed dim permutation identical for A and B => dot/Hamming invariant.
// Writes ALL 160 words/row + rowsum -> poisoned ws regions we read are
// fully initialized.
// ---------------------------------------------------------------------------
__global__ __launch_bounds__(256) void pack_kernel(
    const float* __restrict__ samples, const float* __restrict__ classes,
    unsigned long long* __restrict__ pA, unsigned long long* __restrict__ pB,
    uint32_t* __restrict__ rsA, uint32_t* __restrict__ rsB)
{
    int gwave = (blockIdx.x * 256 + threadIdx.x) >> 6;
    int lane  = threadIdx.x & 63;
    if (gwave >= N_ROWS + C_CLS) return;   // wave-uniform exit

    const float* src;
    unsigned long long* dst;
    uint32_t* rsw;
    if (gwave < N_ROWS) {
        src = samples + (size_t)gwave * D_DIM;
        dst = pA + (size_t)gwave * W64P;
        rsw = rsA + gwave;
    } else {
        int r = gwave - N_ROWS;
        src = classes + (size_t)r * D_DIM;
        dst = pB + (size_t)r * W64P;
        rsw = rsB + r;
    }

    uint32_t rs = 0;
    #pragma unroll 4
    for (int w = 0; w < 40; ++w) {         // 40 * 4 = 160 u64 words
        int idx = w * 256 + lane * 4;      // 16B/lane, coalesced 1KB/wave
        float4 v = make_float4(0.f, 0.f, 0.f, 0.f);
        if (idx < D_DIM) v = *(const float4*)(src + idx);   // D_DIM%4==0
        unsigned long long m0 = __ballot(v.x > 0.5f);
        unsigned long long m1 = __ballot(v.y > 0.5f);
        unsigned long long m2 = __ballot(v.z > 0.5f);
        unsigned long long m3 = __ballot(v.w > 0.5f);
        rs += (uint32_t)(__popcll(m0) + __popcll(m1) + __popcll(m2) + __popcll(m3));
        if (lane == 0) {
            uint4 p0, p1;
            p0.x = (uint32_t)m0; p0.y = (uint32_t)(m0 >> 32);
            p0.z = (uint32_t)m1; p0.w = (uint32_t)(m1 >> 32);
            p1.x = (uint32_t)m2; p1.y = (uint32_t)(m2 >> 32);
            p1.z = (uint32_t)m3; p1.w = (uint32_t)(m3 >> 32);
            *(uint4*)(dst + (size_t)w * 4)     = p0;
            *(uint4*)(dst + (size_t)w * 4 + 2) = p1;
        }
    }
    if (lane == 0) *rsw = rs;
}

// ---------------------------------------------------------------------------
// Kernel 2: dot01 GEMM on matrix cores (v_mfma_i32_32x32x32_i8, {0,1} bytes).
// Block: 256 thr (4 waves, 2x2), tile 128x128; wave tile 64x64 = 2x2 accs.
// Grid 64x8 = 512 blocks. K: 20 chunks of 512 dims.
// LDS: packed bits in PAIRED-transposed layout [step/2][row][2] per operand
// (8 KB each, dbuf -> 32 KB total):
//   reads:  ds_read_b64 = 2 K-steps per instr; rows stride 8 B -> 2-way (free)
//   writes: ds_write_b64 x8 per thread (vs 32 scalar b32 in v3)
// Unpack {0,1}: frag reg j = (word >> (h4+j)) & 0x01010101  (2 VALU/reg,
// half of v3's +-1 form). Induced k-permutation identical A/B -> cancels.
// Per-CU/chunk pipe budget: MFMA 4681 cyc (max) vs VALU ~2048, LDS ~2200.
// Reg-staged global->LDS issued before compute (T14), ONE barrier per chunk.
// ---------------------------------------------------------------------------
__global__ __launch_bounds__(256) void hd_kernel(
    const uint32_t* __restrict__ pA, const uint32_t* __restrict__ pB,
    const uint32_t* __restrict__ rsA, const uint32_t* __restrict__ rsB,
    float* __restrict__ out)
{
    __shared__ uint32_t AsT[2][BKW * 128];   // [buf][pair*256 + row*2 + sub]
    __shared__ uint32_t BsT[2][BKW * 128];

    const int tid  = threadIdx.x;
    const int row0 = blockIdx.x * 128;       // 64 row tiles
    const int col0 = blockIdx.y * 128;       // 8 col tiles (1024 padded)

    const int w    = tid >> 6;               // wave 0..3
    const int lane = tid & 63;
    const int wy   = w >> 1;                 // wave row half (64 rows)
    const int wx   = w & 1;                  // wave col half (64 cols)
    const int ln   = lane & 31;              // row/col within 32-tile
    const int h4   = (lane >> 5) * 4;        // k-half shift base

    // Staging roles: thread covers row srow = tid>>1, 32B half sq2 = (tid&1)*2.
    const int srow = tid >> 1;               // 0..127
    const int sq2  = (tid & 1) * 2;          // quad base 0 or 2 (words 8q..)
    const uint32_t* gAs = pA + (size_t)(row0 + srow) * W32P + sq2 * 4;
    int gc = col0 + srow; if (gc >= C_CLS) gc = C_CLS - 1;  // clamped cols never stored
    const uint32_t* gBs = pB + (size_t)gc * W32P + sq2 * 4;

    uint4 av[2], bv[2];                      // in-flight staging regs (T14)

#define LOADR(ch) do {                                             \
    av[0] = *(const uint4*)(gAs + (ch) * BKW);                     \
    av[1] = *(const uint4*)(gAs + (ch) * BKW + 4);                 \
    bv[0] = *(const uint4*)(gBs + (ch) * BKW);                     \
    bv[1] = *(const uint4*)(gBs + (ch) * BKW + 4);                 \
} while (0)

    // thread's 8 steps = sq2*4 + 0..7 -> pairs p = sq2*2 + i (i=0..3)
    // pair p, row r lives at word index p*256 + r*2 (+ sub)
#define WRITELDS(buf) do {                                         \
    uint32_t* ap_ = &AsT[buf][sq2 * 512 + srow * 2];               \
    uint32_t* bp_ = &BsT[buf][sq2 * 512 + srow * 2];               \
    *(uint2*)(ap_      ) = make_uint2(av[0].x, av[0].y);           \
    *(uint2*)(ap_ + 256) = make_uint2(av[0].z, av[0].w);           \
    *(uint2*)(ap_ + 512) = make_uint2(av[1].x, av[1].y);           \
    *(uint2*)(ap_ + 768) = make_uint2(av[1].z, av[1].w);           \
    *(uint2*)(bp_      ) = make_uint2(bv[0].x, bv[0].y);           \
    *(uint2*)(bp_ + 256) = make_uint2(bv[0].z, bv[0].w);           \
    *(uint2*)(bp_ + 512) = make_uint2(bv[1].x, bv[1].y);           \
    *(uint2*)(bp_ + 768) = make_uint2(bv[1].z, bv[1].w);           \
} while (0)

    // bit-word -> 16 x i8 {0,1} fragment (lane's k-half selected by h4)
#define UNP(dst, src) do {                                         \
    dst[0] = (int)(((src) >> (h4 + 0)) & 0x01010101u);             \
    dst[1] = (int)(((src) >> (h4 + 1)) & 0x01010101u);             \
    dst[2] = (int)(((src) >> (h4 + 2)) & 0x01010101u);             \
    dst[3] = (int)(((src) >> (h4 + 3)) & 0x01010101u);             \
} while (0)

    v16i acc00 = {}, acc01 = {}, acc10 = {}, acc11 = {};

    LOADR(0);
    WRITELDS(0);
    __syncthreads();

    #pragma unroll 2
    for (int ch = 0; ch < NCHUNK; ++ch) {
        const int cur = ch & 1;
        if (ch + 1 < NCHUNK) LOADR(ch + 1);   // issue early; consumed after compute

        const uint32_t* Ac = &AsT[cur][0];
        const uint32_t* Bc = &BsT[cur][0];

        #pragma unroll
        for (int p = 0; p < BKW / 2; ++p) {   // one b64 = 2 K-steps
            uint2 wa0 = *(const uint2*)&Ac[p * 256 + (wy * 64 + ln) * 2];
            uint2 wa1 = *(const uint2*)&Ac[p * 256 + (wy * 64 + 32 + ln) * 2];
            uint2 wb0 = *(const uint2*)&Bc[p * 256 + (wx * 64 + ln) * 2];
            uint2 wb1 = *(const uint2*)&Bc[p * 256 + (wx * 64 + 32 + ln) * 2];
            v4i a0, a1, b0, b1;
            UNP(a0, wa0.x); UNP(a1, wa1.x); UNP(b0, wb0.x); UNP(b1, wb1.x);
            acc00 = __builtin_amdgcn_mfma_i32_32x32x32_i8(a0, b0, acc00, 0, 0, 0);
            acc01 = __builtin_amdgcn_mfma_i32_32x32x32_i8(a0, b1, acc01, 0, 0, 0);
            acc10 = __builtin_amdgcn_mfma_i32_32x32x32_i8(a1, b0, acc10, 0, 0, 0);
            acc11 = __builtin_amdgcn_mfma_i32_32x32x32_i8(a1, b1, acc11, 0, 0, 0);
            UNP(a0, wa0.y); UNP(a1, wa1.y); UNP(b0, wb0.y); UNP(b1, wb1.y);
            acc00 = __builtin_amdgcn_mfma_i32_32x32x32_i8(a0, b0, acc00, 0, 0, 0);
            acc01 = __builtin_amdgcn_mfma_i32_32x32x32_i8(a0, b1, acc01, 0, 0, 0);
            acc10 = __builtin_amdgcn_mfma_i32_32x32x32_i8(a1, b0, acc10, 0, 0, 0);
            acc11 = __builtin_amdgcn_mfma_i32_32x32x32_i8(a1, b1, acc11, 0, 0, 0);
        }

        if (ch + 1 < NCHUNK) {
            WRITELDS((ch + 1) & 1);   // other buffer: disjoint from cur readers
            __syncthreads();          // writes visible before next chunk's reads
        }
    }
#undef LOADR
#undef WRITELDS
#undef UNP

    // ---- epilogue: dist = rsA + rsB - 2*dot01, exact integer -> f32.
    // C/D layout (32x32): col = lane&31, row = (r&3) + 8*(r>>2) + 4*(lane>>5)
    const int gcol0 = col0 + wx * 64 + ln;
    const int gcol1 = gcol0 + 32;
    const uint32_t rb0 = (gcol0 < C_CLS) ? rsB[gcol0] : 0u;
    const uint32_t rb1 = (gcol1 < C_CLS) ? rsB[gcol1] : 0u;
    #pragma unroll
    for (int r = 0; r < 16; ++r) {
        const int m     = (r & 3) + 8 * (r >> 2) + h4;
        const int rowa  = row0 + wy * 64 + m;        // tiles (0,*)
        const int rowb  = rowa + 32;                 // tiles (1,*)
        const uint32_t ra0 = rsA[rowa];
        const uint32_t ra1 = rsA[rowb];
        if (gcol0 < C_CLS) {
            out[(size_t)rowa * C_CLS + gcol0] =
                (float)(int)(ra0 + rb0 - 2u * (uint32_t)acc00[r]);
            out[(size_t)rowb * C_CLS + gcol0] =
                (float)(int)(ra1 + rb0 - 2u * (uint32_t)acc10[r]);
        }
        if (gcol1 < C_CLS) {
            out[(size_t)rowa * C_CLS + gcol1] =
                (float)(int)(ra0 + rb1 - 2u * (uint32_t)acc01[r]);
            out[(size_t)rowb * C_CLS + gcol1] =
                (float)(int)(ra1 + rb1 - 2u * (uint32_t)acc11[r]);
        }
    }
}

extern "C" void kernel_launch(void* const* d_in, const int* in_sizes, int n_in,
                              void* d_out, int out_size, void* d_ws, size_t ws_size,
                              hipStream_t stream) {
    const float* samples = (const float*)d_in[0];   // [8192, 10000] f32
    const float* classes = (const float*)d_in[1];   // [1000, 10000] f32
    float* out = (float*)d_out;                     // [8192, 1000] f32

    // Workspace: packed A (10.49 MB), packed B (1.28 MB), rowsums (36.8 KB).
    unsigned long long* pA = (unsigned long long*)d_ws;
    unsigned long long* pB = pA + (size_t)N_ROWS * W64P;
    uint32_t* rsA = (uint32_t*)(pB + (size_t)C_CLS * W64P);
    uint32_t* rsB = rsA + N_ROWS;

    int waves  = N_ROWS + C_CLS;
    int blocks = (waves + 3) / 4;
    pack_kernel<<<blocks, 256, 0, stream>>>(samples, classes, pA, pB, rsA, rsB);

    dim3 grid(N_ROWS / 128, 8);              // 512 blocks (2 per CU)
    hd_kernel<<<grid, 256, 0, stream>>>((const uint32_t*)pA, (const uint32_t*)pB,
                                        rsA, rsB, out);
}